// Round 2
// baseline (1045.686 us; speedup 1.0000x reference)
//
#include <hip/hip_runtime.h>
#include <hip/hip_bf16.h>

#define D 64

// ---------------------------------------------------------------------------
// K1: per-node message MLP.  m[v] = relu(x[v] @ W1 + b1) @ W2 + b2
// One wave per node; lane j owns output feature j; x[k] broadcast via
// readlane-folded __shfl. Weights staged to LDS (2 x 16 KB fp32).
// ---------------------------------------------------------------------------
__global__ __launch_bounds__(256) void msg_kernel(
    const float* __restrict__ x,
    const float* __restrict__ w1, const float* __restrict__ b1,
    const float* __restrict__ w2, const float* __restrict__ b2,
    float* __restrict__ m, int n_nodes)
{
    __shared__ float sW1[D * D];
    __shared__ float sW2[D * D];
    __shared__ float sB1[D];
    __shared__ float sB2[D];

    for (int i = threadIdx.x; i < D * D; i += 256) {
        sW1[i] = w1[i];
        sW2[i] = w2[i];
    }
    if (threadIdx.x < D) {
        sB1[threadIdx.x] = b1[threadIdx.x];
        sB2[threadIdx.x] = b2[threadIdx.x];
    }
    __syncthreads();

    const int lane   = threadIdx.x & 63;
    const int wid    = (blockIdx.x * blockDim.x + threadIdx.x) >> 6;
    const int nwaves = (gridDim.x * blockDim.x) >> 6;

    for (int v = wid; v < n_nodes; v += nwaves) {
        float xv = x[(size_t)v * D + lane];

        float h = sB1[lane];
#pragma unroll
        for (int k = 0; k < D; ++k) {
            float xk = __shfl(xv, k, 64);
            h = fmaf(xk, sW1[k * D + lane], h);
        }
        h = fmaxf(h, 0.0f);

        float o = sB2[lane];
#pragma unroll
        for (int k = 0; k < D; ++k) {
            float hk = __shfl(h, k, 64);
            o = fmaf(hk, sW2[k * D + lane], o);
        }
        m[(size_t)v * D + lane] = o;
    }
}

// ---------------------------------------------------------------------------
// K2: scatter-sum.  agg[col[e]] += m[row[e]]  (fp32 atomics, coalesced)
// One wave per edge (grid-stride); lane = feature.
// ---------------------------------------------------------------------------
__global__ __launch_bounds__(256) void scatter_kernel(
    const int* __restrict__ row, const int* __restrict__ col,
    const float* __restrict__ m, float* __restrict__ agg, int n_edges)
{
    const int lane   = threadIdx.x & 63;
    const int wid    = (blockIdx.x * blockDim.x + threadIdx.x) >> 6;
    const int nwaves = (gridDim.x * blockDim.x) >> 6;

    for (int e = wid; e < n_edges; e += nwaves) {
        int r = row[e];
        int c = col[e];
        float val = m[(size_t)r * D + lane];
        atomicAdd(&agg[(size_t)c * D + lane], val);
    }
}

// ---------------------------------------------------------------------------
// K3: output MLP.  out[v] = relu([x[v], agg[v]] @ OW1 + ob1) @ OW2 + ob2
// One wave per node; OW1 is 128x64, OW2 is 64x64 (fp32 LDS, 48 KB).
// ---------------------------------------------------------------------------
__global__ __launch_bounds__(256) void out_kernel(
    const float* __restrict__ x, const float* __restrict__ agg,
    const float* __restrict__ w1, const float* __restrict__ b1,
    const float* __restrict__ w2, const float* __restrict__ b2,
    float* __restrict__ out, int n_nodes)
{
    __shared__ float sW1[2 * D * D];   // 128 x 64
    __shared__ float sW2[D * D];       // 64 x 64
    __shared__ float sB1[D];
    __shared__ float sB2[D];

    for (int i = threadIdx.x; i < 2 * D * D; i += 256) sW1[i] = w1[i];
    for (int i = threadIdx.x; i < D * D; i += 256)     sW2[i] = w2[i];
    if (threadIdx.x < D) {
        sB1[threadIdx.x] = b1[threadIdx.x];
        sB2[threadIdx.x] = b2[threadIdx.x];
    }
    __syncthreads();

    const int lane   = threadIdx.x & 63;
    const int wid    = (blockIdx.x * blockDim.x + threadIdx.x) >> 6;
    const int nwaves = (gridDim.x * blockDim.x) >> 6;

    for (int v = wid; v < n_nodes; v += nwaves) {
        float xa = x[(size_t)v * D + lane];     // in[k], k in [0,64)
        float ga = agg[(size_t)v * D + lane];   // in[64+k]

        float h = sB1[lane];
#pragma unroll
        for (int k = 0; k < D; ++k) {
            float xk = __shfl(xa, k, 64);
            h = fmaf(xk, sW1[k * D + lane], h);
        }
#pragma unroll
        for (int k = 0; k < D; ++k) {
            float gk = __shfl(ga, k, 64);
            h = fmaf(gk, sW1[(D + k) * D + lane], h);
        }
        h = fmaxf(h, 0.0f);

        float o = sB2[lane];
#pragma unroll
        for (int k = 0; k < D; ++k) {
            float hk = __shfl(h, k, 64);
            o = fmaf(hk, sW2[k * D + lane], o);
        }
        out[(size_t)v * D + lane] = o;
    }
}

// ---------------------------------------------------------------------------
extern "C" void kernel_launch(void* const* d_in, const int* in_sizes, int n_in,
                              void* d_out, int out_size, void* d_ws, size_t ws_size,
                              hipStream_t stream) {
    const float* x   = (const float*)d_in[0];
    const int*   ei  = (const int*)d_in[1];
    // d_in[2] = batch (unused)
    const float* mw1 = (const float*)d_in[3];
    const float* mb1 = (const float*)d_in[4];
    const float* mw2 = (const float*)d_in[5];
    const float* mb2 = (const float*)d_in[6];
    const float* ow1 = (const float*)d_in[7];
    const float* ob1 = (const float*)d_in[8];
    const float* ow2 = (const float*)d_in[9];
    const float* ob2 = (const float*)d_in[10];

    const int n_nodes = in_sizes[0] / D;        // 100000
    const int n_edges = in_sizes[1] / 2;        // 1000000
    const int* row = ei;                        // edge_index[0]
    const int* col = ei + n_edges;              // edge_index[1]

    float* m   = (float*)d_ws;                  // [n_nodes, 64] fp32
    float* agg = m + (size_t)n_nodes * D;       // [n_nodes, 64] fp32

    hipMemsetAsync(agg, 0, (size_t)n_nodes * D * sizeof(float), stream);

    msg_kernel<<<1024, 256, 0, stream>>>(x, mw1, mb1, mw2, mb2, m, n_nodes);
    scatter_kernel<<<4096, 256, 0, stream>>>(row, col, m, agg, n_edges);
    out_kernel<<<1024, 256, 0, stream>>>(x, agg, ow1, ob1, ow2, ob2,
                                         (float*)d_out, n_nodes);
}

// Round 3
// 342.561 us; speedup vs baseline: 3.0526x; 3.0526x over previous
//
#include <hip/hip_runtime.h>
#include <hip/hip_bf16.h>

#define D 64

typedef __attribute__((ext_vector_type(8))) short bf16x8;   // 8 bf16 in 4 VGPRs
typedef __attribute__((ext_vector_type(4))) float f32x4;

__device__ __forceinline__ short f2bf(float f) {
    __hip_bfloat16 h = __float2bfloat16(f);
    return *reinterpret_cast<short*>(&h);
}

// ---------------------------------------------------------------------------
// K1: per-node message MLP via MFMA.  m[v] = relu(x[v]@W1 + b1)@W2 + b2
// One wave per 16-node tile. Weights live in register B-fragments.
// Layer-1 output goes C-layout -> (LDS, padded) -> A-layout for layer 2.
// ---------------------------------------------------------------------------
__global__ __launch_bounds__(256) void msg_kernel(
    const float* __restrict__ x,
    const float* __restrict__ w1, const float* __restrict__ b1,
    const float* __restrict__ w2, const float* __restrict__ b2,
    float* __restrict__ m, int n_nodes)
{
    __shared__ __align__(16) __hip_bfloat16 sH[4][16 * 72];  // per-wave tile, stride 72 breaks conflicts

    const int lane = threadIdx.x & 63;
    const int wslot = threadIdx.x >> 6;
    const int mr   = lane & 15;   // row within tile / output col
    const int quad = lane >> 4;

    // Hoist weight fragments: B[k][n], lane holds k = ks*32 + quad*8 + j, n = nb*16 + mr
    bf16x8 w1f[2][4], w2f[2][4];
    float  b1v[4], b2v[4];
#pragma unroll
    for (int ks = 0; ks < 2; ++ks)
#pragma unroll
        for (int nb = 0; nb < 4; ++nb) {
            bf16x8 f1, f2;
#pragma unroll
            for (int j = 0; j < 8; ++j) {
                int k = ks * 32 + quad * 8 + j;
                f1[j] = f2bf(w1[k * D + nb * 16 + mr]);
                f2[j] = f2bf(w2[k * D + nb * 16 + mr]);
            }
            w1f[ks][nb] = f1;
            w2f[ks][nb] = f2;
        }
#pragma unroll
    for (int nb = 0; nb < 4; ++nb) {
        b1v[nb] = b1[nb * 16 + mr];
        b2v[nb] = b2[nb * 16 + mr];
    }

    __hip_bfloat16* Hw = sH[wslot];
    const int wid    = (blockIdx.x * blockDim.x + threadIdx.x) >> 6;
    const int nwaves = (gridDim.x * blockDim.x) >> 6;
    const int ntiles = (n_nodes + 15) >> 4;

    for (int t = wid; t < ntiles; t += nwaves) {
        const int v0 = t * 16;
        int vr = v0 + mr;
        if (vr >= n_nodes) vr = n_nodes - 1;

        // A-fragments of x: lane holds x[vr][ks*32 + quad*8 + 0..7]
        bf16x8 a[2];
#pragma unroll
        for (int ks = 0; ks < 2; ++ks) {
            const float* p = x + (size_t)vr * D + ks * 32 + quad * 8;
            float4 lo = *(const float4*)p;
            float4 hi = *(const float4*)(p + 4);
            bf16x8 f;
            f[0] = f2bf(lo.x); f[1] = f2bf(lo.y); f[2] = f2bf(lo.z); f[3] = f2bf(lo.w);
            f[4] = f2bf(hi.x); f[5] = f2bf(hi.y); f[6] = f2bf(hi.z); f[7] = f2bf(hi.w);
            a[ks] = f;
        }

        // Layer 1 + bias + relu -> LDS (bf16)
#pragma unroll
        for (int nb = 0; nb < 4; ++nb) {
            f32x4 acc = {0.f, 0.f, 0.f, 0.f};
            acc = __builtin_amdgcn_mfma_f32_16x16x32_bf16(a[0], w1f[0][nb], acc, 0, 0, 0);
            acc = __builtin_amdgcn_mfma_f32_16x16x32_bf16(a[1], w1f[1][nb], acc, 0, 0, 0);
#pragma unroll
            for (int r = 0; r < 4; ++r) {
                float hv = fmaxf(acc[r] + b1v[nb], 0.f);
                Hw[(quad * 4 + r) * 72 + nb * 16 + mr] = __float2bfloat16(hv);
            }
        }

        // Re-read as A-fragments (wave-private LDS; DS is in-order per wave)
        bf16x8 h[2];
#pragma unroll
        for (int ks = 0; ks < 2; ++ks)
            h[ks] = *(const bf16x8*)&Hw[mr * 72 + ks * 32 + quad * 8];

        // Layer 2 + bias -> global
#pragma unroll
        for (int nb = 0; nb < 4; ++nb) {
            f32x4 acc = {0.f, 0.f, 0.f, 0.f};
            acc = __builtin_amdgcn_mfma_f32_16x16x32_bf16(h[0], w2f[0][nb], acc, 0, 0, 0);
            acc = __builtin_amdgcn_mfma_f32_16x16x32_bf16(h[1], w2f[1][nb], acc, 0, 0, 0);
#pragma unroll
            for (int r = 0; r < 4; ++r) {
                int vrow = v0 + quad * 4 + r;
                if (vrow < n_nodes)
                    m[(size_t)vrow * D + nb * 16 + mr] = acc[r] + b2v[nb];
            }
        }
    }
}

// ---------------------------------------------------------------------------
// K2: scatter-sum.  agg[col[e]] += m[row[e]]  (fp32 atomics, coalesced)
// ---------------------------------------------------------------------------
__global__ __launch_bounds__(256) void scatter_kernel(
    const int* __restrict__ row, const int* __restrict__ col,
    const float* __restrict__ m, float* __restrict__ agg, int n_edges)
{
    const int lane   = threadIdx.x & 63;
    const int wid    = (blockIdx.x * blockDim.x + threadIdx.x) >> 6;
    const int nwaves = (gridDim.x * blockDim.x) >> 6;

    for (int e = wid; e < n_edges; e += nwaves) {
        int r = row[e];
        int c = col[e];
        float val = m[(size_t)r * D + lane];
        atomicAdd(&agg[(size_t)c * D + lane], val);
    }
}

// ---------------------------------------------------------------------------
// K3: output MLP via MFMA.  out[v] = relu([x[v],agg[v]]@OW1 + ob1)@OW2 + ob2
// Layer 1 has K=128 (4 k-steps: 2 from x, 2 from agg).
// ---------------------------------------------------------------------------
__global__ __launch_bounds__(256) void out_kernel(
    const float* __restrict__ x, const float* __restrict__ agg,
    const float* __restrict__ w1, const float* __restrict__ b1,
    const float* __restrict__ w2, const float* __restrict__ b2,
    float* __restrict__ out, int n_nodes)
{
    __shared__ __align__(16) __hip_bfloat16 sH[4][16 * 72];

    const int lane = threadIdx.x & 63;
    const int wslot = threadIdx.x >> 6;
    const int mr   = lane & 15;
    const int quad = lane >> 4;

    bf16x8 w1f[4][4], w2f[2][4];
    float  b1v[4], b2v[4];
#pragma unroll
    for (int ks = 0; ks < 4; ++ks)
#pragma unroll
        for (int nb = 0; nb < 4; ++nb) {
            bf16x8 f;
#pragma unroll
            for (int j = 0; j < 8; ++j) {
                int k = ks * 32 + quad * 8 + j;   // row of OW1 [128 x 64]
                f[j] = f2bf(w1[k * D + nb * 16 + mr]);
            }
            w1f[ks][nb] = f;
        }
#pragma unroll
    for (int ks = 0; ks < 2; ++ks)
#pragma unroll
        for (int nb = 0; nb < 4; ++nb) {
            bf16x8 f;
#pragma unroll
            for (int j = 0; j < 8; ++j) {
                int k = ks * 32 + quad * 8 + j;
                f[j] = f2bf(w2[k * D + nb * 16 + mr]);
            }
            w2f[ks][nb] = f;
        }
#pragma unroll
    for (int nb = 0; nb < 4; ++nb) {
        b1v[nb] = b1[nb * 16 + mr];
        b2v[nb] = b2[nb * 16 + mr];
    }

    __hip_bfloat16* Hw = sH[wslot];
    const int wid    = (blockIdx.x * blockDim.x + threadIdx.x) >> 6;
    const int nwaves = (gridDim.x * blockDim.x) >> 6;
    const int ntiles = (n_nodes + 15) >> 4;

    for (int t = wid; t < ntiles; t += nwaves) {
        const int v0 = t * 16;
        int vr = v0 + mr;
        if (vr >= n_nodes) vr = n_nodes - 1;

        // A-fragments: k 0..63 from x, 64..127 from agg
        bf16x8 a[4];
#pragma unroll
        for (int ks = 0; ks < 4; ++ks) {
            const float* src = (ks < 2) ? (x + (size_t)vr * D + ks * 32)
                                        : (agg + (size_t)vr * D + (ks - 2) * 32);
            const float* p = src + quad * 8;
            float4 lo = *(const float4*)p;
            float4 hi = *(const float4*)(p + 4);
            bf16x8 f;
            f[0] = f2bf(lo.x); f[1] = f2bf(lo.y); f[2] = f2bf(lo.z); f[3] = f2bf(lo.w);
            f[4] = f2bf(hi.x); f[5] = f2bf(hi.y); f[6] = f2bf(hi.z); f[7] = f2bf(hi.w);
            a[ks] = f;
        }

#pragma unroll
        for (int nb = 0; nb < 4; ++nb) {
            f32x4 acc = {0.f, 0.f, 0.f, 0.f};
#pragma unroll
            for (int ks = 0; ks < 4; ++ks)
                acc = __builtin_amdgcn_mfma_f32_16x16x32_bf16(a[ks], w1f[ks][nb], acc, 0, 0, 0);
#pragma unroll
            for (int r = 0; r < 4; ++r) {
                float hv = fmaxf(acc[r] + b1v[nb], 0.f);
                Hw[(quad * 4 + r) * 72 + nb * 16 + mr] = __float2bfloat16(hv);
            }
        }

        bf16x8 h[2];
#pragma unroll
        for (int ks = 0; ks < 2; ++ks)
            h[ks] = *(const bf16x8*)&Hw[mr * 72 + ks * 32 + quad * 8];

#pragma unroll
        for (int nb = 0; nb < 4; ++nb) {
            f32x4 acc = {0.f, 0.f, 0.f, 0.f};
            acc = __builtin_amdgcn_mfma_f32_16x16x32_bf16(h[0], w2f[0][nb], acc, 0, 0, 0);
            acc = __builtin_amdgcn_mfma_f32_16x16x32_bf16(h[1], w2f[1][nb], acc, 0, 0, 0);
#pragma unroll
            for (int r = 0; r < 4; ++r) {
                int vrow = v0 + quad * 4 + r;
                if (vrow < n_nodes)
                    out[(size_t)vrow * D + nb * 16 + mr] = acc[r] + b2v[nb];
            }
        }
    }
}

// ---------------------------------------------------------------------------
extern "C" void kernel_launch(void* const* d_in, const int* in_sizes, int n_in,
                              void* d_out, int out_size, void* d_ws, size_t ws_size,
                              hipStream_t stream) {
    const float* x   = (const float*)d_in[0];
    const int*   ei  = (const int*)d_in[1];
    // d_in[2] = batch (unused)
    const float* mw1 = (const float*)d_in[3];
    const float* mb1 = (const float*)d_in[4];
    const float* mw2 = (const float*)d_in[5];
    const float* mb2 = (const float*)d_in[6];
    const float* ow1 = (const float*)d_in[7];
    const float* ob1 = (const float*)d_in[8];
    const float* ow2 = (const float*)d_in[9];
    const float* ob2 = (const float*)d_in[10];

    const int n_nodes = in_sizes[0] / D;        // 100000
    const int n_edges = in_sizes[1] / 2;        // 1000000
    const int* row = ei;                        // edge_index[0]
    const int* col = ei + n_edges;              // edge_index[1]

    float* m   = (float*)d_ws;                  // [n_nodes, 64] fp32
    float* agg = m + (size_t)n_nodes * D;       // [n_nodes, 64] fp32

    hipMemsetAsync(agg, 0, (size_t)n_nodes * D * sizeof(float), stream);

    const int ntiles = (n_nodes + 15) / 16;     // 6250
    const int nblk   = (ntiles + 3) / 4;        // 4 waves per block

    msg_kernel<<<nblk, 256, 0, stream>>>(x, mw1, mb1, mw2, mb2, m, n_nodes);
    scatter_kernel<<<4096, 256, 0, stream>>>(row, col, m, agg, n_edges);
    out_kernel<<<nblk, 256, 0, stream>>>(x, agg, ow1, ob1, ow2, ob2,
                                         (float*)d_out, n_nodes);
}

// Round 4
// 334.615 us; speedup vs baseline: 3.1250x; 1.0237x over previous
//
#include <hip/hip_runtime.h>
#include <hip/hip_bf16.h>

#define D 64

typedef __attribute__((ext_vector_type(8))) short bf16x8;   // 8 bf16 in 4 VGPRs
typedef __attribute__((ext_vector_type(4))) float f32x4;

__device__ __forceinline__ short f2bf(float f) {
    __hip_bfloat16 h = __float2bfloat16(f);
    return *reinterpret_cast<short*>(&h);
}

// ---------------------------------------------------------------------------
// K1: per-node message MLP via MFMA.  m[v] = relu(x[v]@W1 + b1)@W2 + b2
// One wave per 16-node tile. Weights live in register B-fragments.
// ---------------------------------------------------------------------------
__global__ __launch_bounds__(256) void msg_kernel(
    const float* __restrict__ x,
    const float* __restrict__ w1, const float* __restrict__ b1,
    const float* __restrict__ w2, const float* __restrict__ b2,
    float* __restrict__ m, int n_nodes)
{
    __shared__ __align__(16) __hip_bfloat16 sH[4][16 * 72];

    const int lane = threadIdx.x & 63;
    const int wslot = threadIdx.x >> 6;
    const int mr   = lane & 15;
    const int quad = lane >> 4;

    bf16x8 w1f[2][4], w2f[2][4];
    float  b1v[4], b2v[4];
#pragma unroll
    for (int ks = 0; ks < 2; ++ks)
#pragma unroll
        for (int nb = 0; nb < 4; ++nb) {
            bf16x8 f1, f2;
#pragma unroll
            for (int j = 0; j < 8; ++j) {
                int k = ks * 32 + quad * 8 + j;
                f1[j] = f2bf(w1[k * D + nb * 16 + mr]);
                f2[j] = f2bf(w2[k * D + nb * 16 + mr]);
            }
            w1f[ks][nb] = f1;
            w2f[ks][nb] = f2;
        }
#pragma unroll
    for (int nb = 0; nb < 4; ++nb) {
        b1v[nb] = b1[nb * 16 + mr];
        b2v[nb] = b2[nb * 16 + mr];
    }

    __hip_bfloat16* Hw = sH[wslot];
    const int wid    = (blockIdx.x * blockDim.x + threadIdx.x) >> 6;
    const int nwaves = (gridDim.x * blockDim.x) >> 6;
    const int ntiles = (n_nodes + 15) >> 4;

    for (int t = wid; t < ntiles; t += nwaves) {
        const int v0 = t * 16;
        int vr = v0 + mr;
        if (vr >= n_nodes) vr = n_nodes - 1;

        bf16x8 a[2];
#pragma unroll
        for (int ks = 0; ks < 2; ++ks) {
            const float* p = x + (size_t)vr * D + ks * 32 + quad * 8;
            float4 lo = *(const float4*)p;
            float4 hi = *(const float4*)(p + 4);
            bf16x8 f;
            f[0] = f2bf(lo.x); f[1] = f2bf(lo.y); f[2] = f2bf(lo.z); f[3] = f2bf(lo.w);
            f[4] = f2bf(hi.x); f[5] = f2bf(hi.y); f[6] = f2bf(hi.z); f[7] = f2bf(hi.w);
            a[ks] = f;
        }

#pragma unroll
        for (int nb = 0; nb < 4; ++nb) {
            f32x4 acc = {0.f, 0.f, 0.f, 0.f};
            acc = __builtin_amdgcn_mfma_f32_16x16x32_bf16(a[0], w1f[0][nb], acc, 0, 0, 0);
            acc = __builtin_amdgcn_mfma_f32_16x16x32_bf16(a[1], w1f[1][nb], acc, 0, 0, 0);
#pragma unroll
            for (int r = 0; r < 4; ++r) {
                float hv = fmaxf(acc[r] + b1v[nb], 0.f);
                Hw[(quad * 4 + r) * 72 + nb * 16 + mr] = __float2bfloat16(hv);
            }
        }

        bf16x8 h[2];
#pragma unroll
        for (int ks = 0; ks < 2; ++ks)
            h[ks] = *(const bf16x8*)&Hw[mr * 72 + ks * 32 + quad * 8];

#pragma unroll
        for (int nb = 0; nb < 4; ++nb) {
            f32x4 acc = {0.f, 0.f, 0.f, 0.f};
            acc = __builtin_amdgcn_mfma_f32_16x16x32_bf16(h[0], w2f[0][nb], acc, 0, 0, 0);
            acc = __builtin_amdgcn_mfma_f32_16x16x32_bf16(h[1], w2f[1][nb], acc, 0, 0, 0);
#pragma unroll
            for (int r = 0; r < 4; ++r) {
                int vrow = v0 + quad * 4 + r;
                if (vrow < n_nodes)
                    m[(size_t)vrow * D + nb * 16 + mr] = acc[r] + b2v[nb];
            }
        }
    }
}

// ---------------------------------------------------------------------------
// K2: scatter-sum.  agg[col[e]] += m[row[e]]  (fp32 atomics, coalesced)
// Each wave owns a CONTIGUOUS chunk of 64 edges: indices loaded coalesced
// (one dwordx1 per lane), broadcast via readlane (SGPR addressing), 4 edges
// in flight per step for ILP. Kills the 128 MB strided index overfetch.
// ---------------------------------------------------------------------------
__global__ __launch_bounds__(256) void scatter_kernel(
    const int* __restrict__ row, const int* __restrict__ col,
    const float* __restrict__ m, float* __restrict__ agg, int n_edges)
{
    const int lane = threadIdx.x & 63;
    const int wid  = (blockIdx.x * blockDim.x + threadIdx.x) >> 6;
    const int base = wid * 64;
    if (base >= n_edges) return;

    const int cnt = min(64, n_edges - base);

    int my_r = 0, my_c = 0;
    if (lane < cnt) {
        my_r = row[base + lane];
        my_c = col[base + lane];
    }

    if (cnt == 64) {
#pragma unroll
        for (int jj = 0; jj < 16; ++jj) {
            const int j = jj * 4;
            int r0 = __builtin_amdgcn_readlane(my_r, j + 0);
            int c0 = __builtin_amdgcn_readlane(my_c, j + 0);
            int r1 = __builtin_amdgcn_readlane(my_r, j + 1);
            int c1 = __builtin_amdgcn_readlane(my_c, j + 1);
            int r2 = __builtin_amdgcn_readlane(my_r, j + 2);
            int c2 = __builtin_amdgcn_readlane(my_c, j + 2);
            int r3 = __builtin_amdgcn_readlane(my_r, j + 3);
            int c3 = __builtin_amdgcn_readlane(my_c, j + 3);

            float v0 = m[(size_t)r0 * D + lane];
            float v1 = m[(size_t)r1 * D + lane];
            float v2 = m[(size_t)r2 * D + lane];
            float v3 = m[(size_t)r3 * D + lane];

            atomicAdd(&agg[(size_t)c0 * D + lane], v0);
            atomicAdd(&agg[(size_t)c1 * D + lane], v1);
            atomicAdd(&agg[(size_t)c2 * D + lane], v2);
            atomicAdd(&agg[(size_t)c3 * D + lane], v3);
        }
    } else {
        for (int j = 0; j < cnt; ++j) {
            int r = __builtin_amdgcn_readlane(my_r, j);
            int c = __builtin_amdgcn_readlane(my_c, j);
            float v = m[(size_t)r * D + lane];
            atomicAdd(&agg[(size_t)c * D + lane], v);
        }
    }
}

// ---------------------------------------------------------------------------
// K3: output MLP via MFMA.  out[v] = relu([x[v],agg[v]]@OW1 + ob1)@OW2 + ob2
// ---------------------------------------------------------------------------
__global__ __launch_bounds__(256) void out_kernel(
    const float* __restrict__ x, const float* __restrict__ agg,
    const float* __restrict__ w1, const float* __restrict__ b1,
    const float* __restrict__ w2, const float* __restrict__ b2,
    float* __restrict__ out, int n_nodes)
{
    __shared__ __align__(16) __hip_bfloat16 sH[4][16 * 72];

    const int lane = threadIdx.x & 63;
    const int wslot = threadIdx.x >> 6;
    const int mr   = lane & 15;
    const int quad = lane >> 4;

    bf16x8 w1f[4][4], w2f[2][4];
    float  b1v[4], b2v[4];
#pragma unroll
    for (int ks = 0; ks < 4; ++ks)
#pragma unroll
        for (int nb = 0; nb < 4; ++nb) {
            bf16x8 f;
#pragma unroll
            for (int j = 0; j < 8; ++j) {
                int k = ks * 32 + quad * 8 + j;
                f[j] = f2bf(w1[k * D + nb * 16 + mr]);
            }
            w1f[ks][nb] = f;
        }
#pragma unroll
    for (int ks = 0; ks < 2; ++ks)
#pragma unroll
        for (int nb = 0; nb < 4; ++nb) {
            bf16x8 f;
#pragma unroll
            for (int j = 0; j < 8; ++j) {
                int k = ks * 32 + quad * 8 + j;
                f[j] = f2bf(w2[k * D + nb * 16 + mr]);
            }
            w2f[ks][nb] = f;
        }
#pragma unroll
    for (int nb = 0; nb < 4; ++nb) {
        b1v[nb] = b1[nb * 16 + mr];
        b2v[nb] = b2[nb * 16 + mr];
    }

    __hip_bfloat16* Hw = sH[wslot];
    const int wid    = (blockIdx.x * blockDim.x + threadIdx.x) >> 6;
    const int nwaves = (gridDim.x * blockDim.x) >> 6;
    const int ntiles = (n_nodes + 15) >> 4;

    for (int t = wid; t < ntiles; t += nwaves) {
        const int v0 = t * 16;
        int vr = v0 + mr;
        if (vr >= n_nodes) vr = n_nodes - 1;

        bf16x8 a[4];
#pragma unroll
        for (int ks = 0; ks < 4; ++ks) {
            const float* src = (ks < 2) ? (x + (size_t)vr * D + ks * 32)
                                        : (agg + (size_t)vr * D + (ks - 2) * 32);
            const float* p = src + quad * 8;
            float4 lo = *(const float4*)p;
            float4 hi = *(const float4*)(p + 4);
            bf16x8 f;
            f[0] = f2bf(lo.x); f[1] = f2bf(lo.y); f[2] = f2bf(lo.z); f[3] = f2bf(lo.w);
            f[4] = f2bf(hi.x); f[5] = f2bf(hi.y); f[6] = f2bf(hi.z); f[7] = f2bf(hi.w);
            a[ks] = f;
        }

#pragma unroll
        for (int nb = 0; nb < 4; ++nb) {
            f32x4 acc = {0.f, 0.f, 0.f, 0.f};
#pragma unroll
            for (int ks = 0; ks < 4; ++ks)
                acc = __builtin_amdgcn_mfma_f32_16x16x32_bf16(a[ks], w1f[ks][nb], acc, 0, 0, 0);
#pragma unroll
            for (int r = 0; r < 4; ++r) {
                float hv = fmaxf(acc[r] + b1v[nb], 0.f);
                Hw[(quad * 4 + r) * 72 + nb * 16 + mr] = __float2bfloat16(hv);
            }
        }

        bf16x8 h[2];
#pragma unroll
        for (int ks = 0; ks < 2; ++ks)
            h[ks] = *(const bf16x8*)&Hw[mr * 72 + ks * 32 + quad * 8];

#pragma unroll
        for (int nb = 0; nb < 4; ++nb) {
            f32x4 acc = {0.f, 0.f, 0.f, 0.f};
            acc = __builtin_amdgcn_mfma_f32_16x16x32_bf16(h[0], w2f[0][nb], acc, 0, 0, 0);
            acc = __builtin_amdgcn_mfma_f32_16x16x32_bf16(h[1], w2f[1][nb], acc, 0, 0, 0);
#pragma unroll
            for (int r = 0; r < 4; ++r) {
                int vrow = v0 + quad * 4 + r;
                if (vrow < n_nodes)
                    out[(size_t)vrow * D + nb * 16 + mr] = acc[r] + b2v[nb];
            }
        }
    }
}

// ---------------------------------------------------------------------------
extern "C" void kernel_launch(void* const* d_in, const int* in_sizes, int n_in,
                              void* d_out, int out_size, void* d_ws, size_t ws_size,
                              hipStream_t stream) {
    const float* x   = (const float*)d_in[0];
    const int*   ei  = (const int*)d_in[1];
    // d_in[2] = batch (unused)
    const float* mw1 = (const float*)d_in[3];
    const float* mb1 = (const float*)d_in[4];
    const float* mw2 = (const float*)d_in[5];
    const float* mb2 = (const float*)d_in[6];
    const float* ow1 = (const float*)d_in[7];
    const float* ob1 = (const float*)d_in[8];
    const float* ow2 = (const float*)d_in[9];
    const float* ob2 = (const float*)d_in[10];

    const int n_nodes = in_sizes[0] / D;        // 100000
    const int n_edges = in_sizes[1] / 2;        // 1000000
    const int* row = ei;                        // edge_index[0]
    const int* col = ei + n_edges;              // edge_index[1]

    float* m   = (float*)d_ws;                  // [n_nodes, 64] fp32
    float* agg = m + (size_t)n_nodes * D;       // [n_nodes, 64] fp32

    hipMemsetAsync(agg, 0, (size_t)n_nodes * D * sizeof(float), stream);

    const int ntiles = (n_nodes + 15) / 16;     // 6250
    const int nblk   = (ntiles + 3) / 4;        // 4 waves per block

    msg_kernel<<<nblk, 256, 0, stream>>>(x, mw1, mb1, mw2, mb2, m, n_nodes);

    const int nwaves_s = (n_edges + 63) / 64;   // one wave per 64 edges
    const int nblk_s   = (nwaves_s + 3) / 4;
    scatter_kernel<<<nblk_s, 256, 0, stream>>>(row, col, m, agg, n_edges);

    out_kernel<<<nblk, 256, 0, stream>>>(x, agg, ow1, ob1, ow2, ob2,
                                         (float*)d_out, n_nodes);
}